// Round 1
// baseline (68183.844 us; speedup 1.0000x reference)
//
#include <hip/hip_runtime.h>
#include <hip/hip_cooperative_groups.h>
#include <math.h>

// Problem constants (from reference)
#define NUM_PB 32
#define PBDIM  16
#define DDIM   64
#define HDIM   1024
#define BDIM   64

namespace cg = cooperative_groups;

struct Params {
    const int*   label;     // [B]
    const int*   fcl;       // [1] forward_computation_length
    const float* mu_pb;     // [NUM_PB, PBDIM]
    const float* logvar_pb; // [NUM_PB, PBDIM]
    const float* Wi0;       // [4H, D+PB]
    const float* Wh0;       // [4H, H]
    const float* bi0;       // [4H]
    const float* bh0;       // [4H]
    const float* Wi1;       // [4H, H]
    const float* Wh1;       // [4H, H]
    const float* bi1;       // [4H]
    const float* bh1;       // [4H]
    const float* Wlin;      // [D, H]
    const float* blin;      // [D]
    float*       out;       // concatenated outputs (float32)
    float*       ws;        // scratch
};

__device__ __forceinline__ float sigmoidf_(float x) {
    return 1.0f / (1.0f + __expf(-x));
}

// Accumulate 4 gate dot-products over K elements.
// W rows: gate g row index = g*HDIM + j, row length/stride = K (contiguous fp32).
// xcol points at x[0][b]; x stored transposed [K][BDIM] so x[k][b] = xcol[k*BDIM].
__device__ __forceinline__ void dot4gates(const float* __restrict__ W, int j, int K,
                                          const float* __restrict__ xcol,
                                          float& ai, float& af, float& ag, float& ao) {
    const float* wi = W + (size_t)(0 * HDIM + j) * K;
    const float* wf = W + (size_t)(1 * HDIM + j) * K;
    const float* wg = W + (size_t)(2 * HDIM + j) * K;
    const float* wo = W + (size_t)(3 * HDIM + j) * K;
#pragma unroll 2
    for (int k = 0; k < K; k += 4) {
        float x0 = xcol[(k + 0) * BDIM];
        float x1 = xcol[(k + 1) * BDIM];
        float x2 = xcol[(k + 2) * BDIM];
        float x3 = xcol[(k + 3) * BDIM];
        float4 vi = *(const float4*)(wi + k);
        float4 vf = *(const float4*)(wf + k);
        float4 vg = *(const float4*)(wg + k);
        float4 vo = *(const float4*)(wo + k);
        ai = fmaf(vi.x, x0, fmaf(vi.y, x1, fmaf(vi.z, x2, fmaf(vi.w, x3, ai))));
        af = fmaf(vf.x, x0, fmaf(vf.y, x1, fmaf(vf.z, x2, fmaf(vf.w, x3, af))));
        ag = fmaf(vg.x, x0, fmaf(vg.y, x1, fmaf(vg.z, x2, fmaf(vg.w, x3, ag))));
        ao = fmaf(vo.x, x0, fmaf(vo.y, x1, fmaf(vo.z, x2, fmaf(vo.w, x3, ao))));
    }
}

// Grid: 256 blocks x 256 threads. Thread owns (b = tid&63, j = bid*4 + tid>>6).
// Persistent: c0,c1 in registers across all T steps; h double-buffered in ws,
// stored transposed [H][B] for coalesced batch-contiguous loads.
__global__ void __launch_bounds__(256, 1) rnn_kernel(Params p) {
    cg::grid_group grid = cg::this_grid();
    const int tid = threadIdx.x;
    const int bid = blockIdx.x;
    const int b   = tid & 63;
    const int j   = bid * 4 + (tid >> 6);   // 0..1023
    const int T   = p.fcl[0];

    float* xT  = p.ws;                       // [D+PB][B] = [80][64]
    float* h0T = xT + (DDIM + PBDIM) * BDIM; // 2 buffers of [H][B]
    float* h1T = h0T + 2 * HDIM * BDIM;      // 2 buffers of [H][B]

    // ---- init (ws and d_out are poisoned 0xAA before every launch) ----
    {
        int g = bid * 256 + tid;             // 0..65535 == HDIM*BDIM
        h0T[g] = 0.0f;                       // buffer 0 of h0
        h1T[g] = 0.0f;                       // buffer 0 of h1
        if (g < DDIM * BDIM) xT[g] = 0.0f;   // y_prev = 0 rows
        if (bid == 0 && tid < BDIM) {
            int lbl = p.label[tid];
            float* out_lbl = p.out + (size_t)T * BDIM * DDIM;
            float* out_pb  = out_lbl + BDIM;
            float* out_mu  = out_pb + BDIM * PBDIM;
            float* out_lv  = out_mu + BDIM * PBDIM;
            out_lbl[tid] = (float)lbl;
            for (int q = 0; q < PBDIM; ++q) {
                float mu = p.mu_pb[lbl * PBDIM + q];
                float lv = p.logvar_pb[lbl * PBDIM + q];
                out_pb[tid * PBDIM + q] = mu;   // pb (deterministic = mu)
                out_mu[tid * PBDIM + q] = mu;   // mu_sel
                out_lv[tid * PBDIM + q] = lv;   // logvar_sel
                xT[(DDIM + q) * BDIM + tid] = mu; // pb rows of x (constant over t)
            }
        }
    }

    // per-thread persistent state
    float c0 = 0.0f, c1 = 0.0f;
    // fold the two bias vectors per gate (constant over t)
    const float bI0 = p.bi0[0 * HDIM + j] + p.bh0[0 * HDIM + j];
    const float bF0 = p.bi0[1 * HDIM + j] + p.bh0[1 * HDIM + j];
    const float bG0 = p.bi0[2 * HDIM + j] + p.bh0[2 * HDIM + j];
    const float bO0 = p.bi0[3 * HDIM + j] + p.bh0[3 * HDIM + j];
    const float bI1 = p.bi1[0 * HDIM + j] + p.bh1[0 * HDIM + j];
    const float bF1 = p.bi1[1 * HDIM + j] + p.bh1[1 * HDIM + j];
    const float bG1 = p.bi1[2 * HDIM + j] + p.bh1[2 * HDIM + j];
    const float bO1 = p.bi1[3 * HDIM + j] + p.bh1[3 * HDIM + j];

    grid.sync();

    int cur = 0;
    for (int t = 0; t < T; ++t) {
        // ---- phase 1: layer 0.  x = [y_prev; pb] (xT), h = h0T[cur] ----
        {
            float ai = bI0, af = bF0, ag = bG0, ao = bO0;
            dot4gates(p.Wi0, j, DDIM + PBDIM, xT + b, ai, af, ag, ao);
            dot4gates(p.Wh0, j, HDIM, h0T + (size_t)cur * HDIM * BDIM + b, ai, af, ag, ao);
            float iv = sigmoidf_(ai), fv = sigmoidf_(af);
            float gv = tanhf(ag),    ov = sigmoidf_(ao);
            c0 = fv * c0 + iv * gv;
            float hn = ov * tanhf(c0);
            h0T[(size_t)(cur ^ 1) * HDIM * BDIM + j * BDIM + b] = hn;
        }
        grid.sync();
        // ---- phase 2: layer 1.  x = h0_new (h0T[cur^1]), h = h1T[cur] ----
        {
            float ai = bI1, af = bF1, ag = bG1, ao = bO1;
            dot4gates(p.Wi1, j, HDIM, h0T + (size_t)(cur ^ 1) * HDIM * BDIM + b, ai, af, ag, ao);
            dot4gates(p.Wh1, j, HDIM, h1T + (size_t)cur * HDIM * BDIM + b, ai, af, ag, ao);
            float iv = sigmoidf_(ai), fv = sigmoidf_(af);
            float gv = tanhf(ag),    ov = sigmoidf_(ao);
            c1 = fv * c1 + iv * gv;
            float hn = ov * tanhf(c1);
            h1T[(size_t)(cur ^ 1) * HDIM * BDIM + j * BDIM + b] = hn;
        }
        grid.sync();
        // ---- phase 3: readout  out[t] = h1_new @ Wlin^T + blin; feeds next x ----
        if (bid < 16) {
            int g  = bid * 256 + tid;    // 0..4095
            int ob = g & 63;
            int d  = g >> 6;             // 0..63
            const float* h = h1T + (size_t)(cur ^ 1) * HDIM * BDIM + ob;
            const float* w = p.Wlin + (size_t)d * HDIM;
            float acc = p.blin[d];
#pragma unroll 2
            for (int k = 0; k < HDIM; k += 4) {
                float4 wv = *(const float4*)(w + k);
                acc = fmaf(wv.x, h[(k + 0) * BDIM],
                      fmaf(wv.y, h[(k + 1) * BDIM],
                      fmaf(wv.z, h[(k + 2) * BDIM],
                      fmaf(wv.w, h[(k + 3) * BDIM], acc))));
            }
            p.out[(size_t)t * BDIM * DDIM + ob * DDIM + d] = acc;
            xT[d * BDIM + ob] = acc;     // y_prev rows of next x
        }
        grid.sync();
        cur ^= 1;
    }
}

extern "C" void kernel_launch(void* const* d_in, const int* in_sizes, int n_in,
                              void* d_out, int out_size, void* d_ws, size_t ws_size,
                              hipStream_t stream) {
    Params p;
    p.label     = (const int*)d_in[0];
    p.fcl       = (const int*)d_in[1];
    p.mu_pb     = (const float*)d_in[2];
    p.logvar_pb = (const float*)d_in[3];
    p.Wi0       = (const float*)d_in[4];
    p.Wh0       = (const float*)d_in[5];
    p.bi0       = (const float*)d_in[6];
    p.bh0       = (const float*)d_in[7];
    p.Wi1       = (const float*)d_in[8];
    p.Wh1       = (const float*)d_in[9];
    p.bi1       = (const float*)d_in[10];
    p.bh1       = (const float*)d_in[11];
    p.Wlin      = (const float*)d_in[12];
    p.blin      = (const float*)d_in[13];
    p.out       = (float*)d_out;
    p.ws        = (float*)d_ws;

    void* args[] = { &p };
    dim3 grid(256), block(256);
    hipLaunchCooperativeKernel((void*)rnn_kernel, grid, block, args, 0, stream);
}

// Round 2
// 32918.640 us; speedup vs baseline: 2.0713x; 2.0713x over previous
//
#include <hip/hip_runtime.h>
#include <hip/hip_cooperative_groups.h>
#include <math.h>

#define NUM_PB 32
#define PBDIM  16
#define DDIM   64
#define HDIM   1024
#define BDIM   64

namespace cg = cooperative_groups;

typedef __attribute__((ext_vector_type(8))) short bf16x8;
typedef __attribute__((ext_vector_type(4))) float f32x4;

// LDS layout (ushort elements)
#define WI0_ST 104              // 96 + 8 pad
#define WH_ST  1032             // 1024 + 8 pad
#define SX_ST  136              // 128 + 8 pad
#define SX_BUF (64 * SX_ST)     // 8704
#define SW_ELEMS (16 * WI0_ST + 3 * 16 * WH_ST)   // 1664 + 49536 = 51200
#define SMEM_BYTES ((SW_ELEMS + 2 * SX_BUF) * 2)  // 137216 B <= 160 KiB

struct Params {
    const int*   label;
    const int*   fcl;
    const float* mu_pb;
    const float* logvar_pb;
    const float* Wi0;
    const float* Wh0;
    const float* bi0;
    const float* bh0;
    const float* Wi1;
    const float* Wh1;
    const float* bi1;
    const float* bh1;
    const float* Wlin;
    const float* blin;
    float*       out;
    float*       ws;
};

__device__ __forceinline__ unsigned short f2bf(float x) {
    unsigned int u = __builtin_bit_cast(unsigned int, x);
    u += 0x7fffu + ((u >> 16) & 1u);            // RNE
    return (unsigned short)(u >> 16);
}
__device__ __forceinline__ float sigf(float x)   { return 1.0f / (1.0f + __expf(-x)); }
__device__ __forceinline__ float tanh_(float x)  { float e = __expf(2.0f * x); return 1.0f - 2.0f / (e + 1.0f); }

// Stage one [64][128]-bf16 chunk: global (row stride strideE elems) -> regs
__device__ __forceinline__ void load_chunk(uint4* pf, const unsigned short* __restrict__ g,
                                           int strideE, int kbase, int tid) {
    int row = tid >> 2, seg = tid & 3;
    const uint4* src = (const uint4*)(g + (size_t)row * strideE + kbase);
#pragma unroll
    for (int i = 0; i < 4; ++i) pf[i] = src[seg * 4 + i];
}
__device__ __forceinline__ void store_chunk(const uint4* pf, unsigned short* s, int tid) {
    int row = tid >> 2, seg = tid & 3;
    uint4* dst = (uint4*)(s + row * SX_ST);
#pragma unroll
    for (int i = 0; i < 4; ++i) dst[seg * 4 + i] = pf[i];
}

// C[16 rows][64 cols] += A(16 x Kmfma, LDS, row stride AstE) * X(gX: [64][strideE] bf16 global, transposed)
// Double-buffered sX staging, 1-chunk-ahead register prefetch, 1 syncthreads/chunk.
__device__ __forceinline__ void gemm_mat(const unsigned short* __restrict__ sA, int AstE,
                                         const unsigned short* __restrict__ gX, int gStrideE,
                                         int Kstage, int Kmfma, unsigned short* sX,
                                         int tid, int lm, int lq, int bcol0,
                                         f32x4* accs, int& ks, int& par) {
    int nchunk = Kstage >> 7;
    uint4 pf[4];
    load_chunk(pf, gX, gStrideE, 0, tid);
    for (int c = 0; c < nchunk; ++c) {
        unsigned short* buf = sX + (par & 1) * SX_BUF; ++par;
        store_chunk(pf, buf, tid);
        if (c + 1 < nchunk) load_chunk(pf, gX, gStrideE, (c + 1) << 7, tid);
        __syncthreads();
        int kleft = Kmfma - (c << 7);
        int nkb = kleft >= 128 ? 4 : (kleft >> 5);
        const unsigned short* Ab = sA + lm * AstE + (c << 7) + 8 * lq;
        const unsigned short* Bb = buf + (bcol0 + lm) * SX_ST + 8 * lq;
        for (int kb = 0; kb < nkb; ++kb) {
            bf16x8 a = *(const bf16x8*)(Ab + kb * 32);
            bf16x8 b = *(const bf16x8*)(Bb + kb * 32);
            accs[ks & 3] = __builtin_amdgcn_mfma_f32_16x16x32_bf16(a, b, accs[ks & 3], 0, 0, 0);
            ++ks;
        }
    }
}

// Same, but A fragments loaded straight from global bf16 (row stride AstE elems).
__device__ __forceinline__ void gemm_mat_gA(const unsigned short* __restrict__ gA, int AstE,
                                            const unsigned short* __restrict__ gX, int gStrideE,
                                            int Kstage, int Kmfma, unsigned short* sX,
                                            int tid, int lm, int lq, int bcol0,
                                            f32x4* accs, int& ks, int& par) {
    int nchunk = Kstage >> 7;
    uint4 pf[4];
    load_chunk(pf, gX, gStrideE, 0, tid);
    for (int c = 0; c < nchunk; ++c) {
        unsigned short* buf = sX + (par & 1) * SX_BUF; ++par;
        store_chunk(pf, buf, tid);
        if (c + 1 < nchunk) load_chunk(pf, gX, gStrideE, (c + 1) << 7, tid);
        __syncthreads();
        int kleft = Kmfma - (c << 7);
        int nkb = kleft >= 128 ? 4 : (kleft >> 5);
        const unsigned short* Ab = gA + lm * AstE + (c << 7) + 8 * lq;
        const unsigned short* Bb = buf + (bcol0 + lm) * SX_ST + 8 * lq;
        for (int kb = 0; kb < nkb; ++kb) {
            bf16x8 a = *(const bf16x8*)(Ab + kb * 32);
            bf16x8 b = *(const bf16x8*)(Bb + kb * 32);
            accs[ks & 3] = __builtin_amdgcn_mfma_f32_16x16x32_bf16(a, b, accs[ks & 3], 0, 0, 0);
            ++ks;
        }
    }
}

// 256 blocks x 256 threads, 1 block/CU (134 KB LDS). Block owns j0=bid*4 (16 gate-rows,
// ordered m=jq*4+gate so MFMA C/D gives each lane all 4 gates of one (j,b) cell:
// lane quad lq = jq, reg r = gate, col lm = b-within-wave-tile. c-state in registers.
__global__ void __launch_bounds__(256, 1) rnn_kernel(Params p) {
    extern __shared__ __align__(16) unsigned short smem[];
    unsigned short* sWi0 = smem;
    unsigned short* sWh0 = sWi0 + 16 * WI0_ST;
    unsigned short* sWi1 = sWh0 + 16 * WH_ST;
    unsigned short* sWh1 = sWi1 + 16 * WH_ST;
    unsigned short* sX   = smem + SW_ELEMS;

    cg::grid_group grid = cg::this_grid();
    const int tid = threadIdx.x, bid = blockIdx.x;
    const int lane = tid & 63, w = tid >> 6;
    const int lm = lane & 15, lq = lane >> 4;
    const int bcol0 = w * 16;
    const int bb = bcol0 + lm;            // batch column this lane owns in frags
    const int j0 = bid * 4, jj = j0 + lq; // hidden unit this lane owns
    const int T = p.fcl[0];

    // workspace (ushort): x80[64][128] | h0[2][64][1024] | h1[2][64][1024] | wlin_bf[64][1024]
    unsigned short* x80g = (unsigned short*)p.ws;
    unsigned short* h0g  = x80g + 64 * 128;
    unsigned short* h1g  = h0g + 2 * 65536;
    unsigned short* wlg  = h1g + 2 * 65536;

    // ---------------- init ----------------
    for (int idx = tid; idx < 16 * 1024; idx += 256) {
        int m = idx >> 10, k = idx & 1023;
        int gi = m & 3, jq = m >> 2;
        size_t row = (size_t)(gi * HDIM + j0 + jq);
        sWh0[m * WH_ST + k] = f2bf(p.Wh0[row * HDIM + k]);
        sWi1[m * WH_ST + k] = f2bf(p.Wi1[row * HDIM + k]);
        sWh1[m * WH_ST + k] = f2bf(p.Wh1[row * HDIM + k]);
    }
    for (int idx = tid; idx < 16 * WI0_ST; idx += 256) {
        int m = idx / WI0_ST, k = idx - m * WI0_ST;
        int gi = m & 3, jq = m >> 2;
        unsigned short v = 0;
        if (k < DDIM + PBDIM) v = f2bf(p.Wi0[(size_t)(gi * HDIM + j0 + jq) * (DDIM + PBDIM) + k]);
        sWi0[idx] = v;
    }
    int gid = bid * 256 + tid;            // 0..65535
    h0g[gid] = 0;                         // zero buffer 0 of h0, h1
    h1g[gid] = 0;
    if (gid < 64 * 128) {                 // x80: [y(0..63)=0 | pb(64..79) | zero pad(80..127)]
        int b = gid >> 7, k = gid & 127;
        unsigned short v = 0;
        if (k >= 64 && k < 80) v = f2bf(p.mu_pb[p.label[b] * PBDIM + (k - 64)]);
        x80g[gid] = v;
    }
    if (bid < 16) {                       // Wlin -> bf16 global, row-major [64][1024]
        for (int i = 0; i < 16; ++i) {
            int e = bid * 4096 + i * 256 + tid;
            wlg[e] = f2bf(p.Wlin[e]);
        }
    }
    if (bid == 16 && tid < BDIM) {        // aux outputs
        int lbl = p.label[tid];
        float* out_lbl = p.out + (size_t)T * BDIM * DDIM;
        float* out_pb  = out_lbl + BDIM;
        float* out_mu  = out_pb + BDIM * PBDIM;
        float* out_lv  = out_mu + BDIM * PBDIM;
        out_lbl[tid] = (float)lbl;
        for (int q = 0; q < PBDIM; ++q) {
            float mu = p.mu_pb[lbl * PBDIM + q];
            float lv = p.logvar_pb[lbl * PBDIM + q];
            out_pb[tid * PBDIM + q] = mu;
            out_mu[tid * PBDIM + q] = mu;
            out_lv[tid * PBDIM + q] = lv;
        }
    }
    float bias0[4], bias1[4];
#pragma unroll
    for (int r = 0; r < 4; ++r) {
        bias0[r] = p.bi0[r * HDIM + jj] + p.bh0[r * HDIM + jj];
        bias1[r] = p.bi1[r * HDIM + jj] + p.bh1[r * HDIM + jj];
    }
    float blin4[4] = {0.f, 0.f, 0.f, 0.f};
    if (bid < 4) {
        int d0 = bid * 16 + lq * 4;
#pragma unroll
        for (int r = 0; r < 4; ++r) blin4[r] = p.blin[d0 + r];
    }
    float c0 = 0.f, c1 = 0.f;

    grid.sync();

    const f32x4 zf = {0.f, 0.f, 0.f, 0.f};
    int cur = 0;
    for (int t = 0; t < T; ++t) {
        // ---- layer 0: gates = Wi0*[y;pb] + Wh0*h0 ----
        f32x4 accs[4] = {zf, zf, zf, zf};
        int ks = 0, par = 0;
        gemm_mat(sWi0, WI0_ST, x80g, 128, 128, 96, sX, tid, lm, lq, bcol0, accs, ks, par);
        gemm_mat(sWh0, WH_ST, h0g + cur * 65536, 1024, 1024, 1024, sX, tid, lm, lq, bcol0, accs, ks, par);
        {
            f32x4 s = accs[0] + accs[1] + accs[2] + accs[3];
            float gi_ = s[0] + bias0[0], gf_ = s[1] + bias0[1];
            float gg_ = s[2] + bias0[2], go_ = s[3] + bias0[3];
            c0 = sigf(gf_) * c0 + sigf(gi_) * tanh_(gg_);
            float h = sigf(go_) * tanh_(c0);
            h0g[(cur ^ 1) * 65536 + bb * 1024 + jj] = f2bf(h);
        }
        grid.sync();
        // ---- layer 1: gates = Wi1*h0new + Wh1*h1 ----
        accs[0] = zf; accs[1] = zf; accs[2] = zf; accs[3] = zf; ks = 0; par = 0;
        gemm_mat(sWi1, WH_ST, h0g + (cur ^ 1) * 65536, 1024, 1024, 1024, sX, tid, lm, lq, bcol0, accs, ks, par);
        gemm_mat(sWh1, WH_ST, h1g + cur * 65536, 1024, 1024, 1024, sX, tid, lm, lq, bcol0, accs, ks, par);
        {
            f32x4 s = accs[0] + accs[1] + accs[2] + accs[3];
            float gi_ = s[0] + bias1[0], gf_ = s[1] + bias1[1];
            float gg_ = s[2] + bias1[2], go_ = s[3] + bias1[3];
            c1 = sigf(gf_) * c1 + sigf(gi_) * tanh_(gg_);
            float h = sigf(go_) * tanh_(c1);
            h1g[(cur ^ 1) * 65536 + bb * 1024 + jj] = f2bf(h);
        }
        grid.sync();
        // ---- readout: y = Wlin*h1new + blin (blocks 0..3, 16 d-rows each) ----
        if (bid < 4) {
            accs[0] = zf; accs[1] = zf; accs[2] = zf; accs[3] = zf; ks = 0; par = 0;
            gemm_mat_gA(wlg + bid * 16 * 1024, 1024, h1g + (cur ^ 1) * 65536, 1024, 1024, 1024,
                        sX, tid, lm, lq, bcol0, accs, ks, par);
            f32x4 s = accs[0] + accs[1] + accs[2] + accs[3];
            int d0 = bid * 16 + lq * 4;
            float4 y4;
            y4.x = s[0] + blin4[0]; y4.y = s[1] + blin4[1];
            y4.z = s[2] + blin4[2]; y4.w = s[3] + blin4[3];
            *(float4*)(p.out + (size_t)t * BDIM * DDIM + bb * DDIM + d0) = y4;
            ushort4 u4;
            u4.x = f2bf(y4.x); u4.y = f2bf(y4.y); u4.z = f2bf(y4.z); u4.w = f2bf(y4.w);
            *(ushort4*)(x80g + bb * 128 + d0) = u4;
        }
        grid.sync();
        cur ^= 1;
    }
}

extern "C" void kernel_launch(void* const* d_in, const int* in_sizes, int n_in,
                              void* d_out, int out_size, void* d_ws, size_t ws_size,
                              hipStream_t stream) {
    Params p;
    p.label     = (const int*)d_in[0];
    p.fcl       = (const int*)d_in[1];
    p.mu_pb     = (const float*)d_in[2];
    p.logvar_pb = (const float*)d_in[3];
    p.Wi0       = (const float*)d_in[4];
    p.Wh0       = (const float*)d_in[5];
    p.bi0       = (const float*)d_in[6];
    p.bh0       = (const float*)d_in[7];
    p.Wi1       = (const float*)d_in[8];
    p.Wh1       = (const float*)d_in[9];
    p.bi1       = (const float*)d_in[10];
    p.bh1       = (const float*)d_in[11];
    p.Wlin      = (const float*)d_in[12];
    p.blin      = (const float*)d_in[13];
    p.out       = (float*)d_out;
    p.ws        = (float*)d_ws;

    (void)hipFuncSetAttribute((const void*)rnn_kernel,
                              hipFuncAttributeMaxDynamicSharedMemorySize, SMEM_BYTES);
    void* args[] = { &p };
    (void)hipLaunchCooperativeKernel((void*)rnn_kernel, dim3(256), dim3(256), args,
                                     SMEM_BYTES, stream);
}

// Round 4
// 28034.344 us; speedup vs baseline: 2.4322x; 1.1742x over previous
//
#include <hip/hip_runtime.h>
#include <hip/hip_cooperative_groups.h>
#include <math.h>

#define NUM_PB 32
#define PBDIM  16
#define DDIM   64
#define HDIM   1024
#define BDIM   64

namespace cg = cooperative_groups;

typedef __attribute__((ext_vector_type(8))) short bf16x8;
typedef __attribute__((ext_vector_type(4))) float f32x4;

// LDS: weights only. strides in shorts; both give 16B-aligned rows.
#define WI0_ST 104                       // 96 + 8 pad (208 B = 13*16)
#define WST    1032                      // 1024 + 8 pad (2064 B = 129*16)
#define SMEM_BYTES ((16 * WI0_ST + 3 * 16 * WST) * 2)   // 102400 B

struct Params {
    const int*   label;
    const int*   fcl;
    const float* mu_pb;
    const float* logvar_pb;
    const float* Wi0;
    const float* Wh0;
    const float* bi0;
    const float* bh0;
    const float* Wi1;
    const float* Wh1;
    const float* bi1;
    const float* bh1;
    const float* Wlin;
    const float* blin;
    float*       out;
    float*       ws;
};

__device__ __forceinline__ unsigned short f2bf(float x) {
    unsigned int u = __builtin_bit_cast(unsigned int, x);
    u += 0x7fffu + ((u >> 16) & 1u);     // RNE
    return (unsigned short)(u >> 16);
}
__device__ __forceinline__ float sigf(float x)  { return 1.0f / (1.0f + __expf(-x)); }
__device__ __forceinline__ float tanh_(float x) { float e = __expf(2.0f * x); return 1.0f - 2.0f / (e + 1.0f); }

// NKB MFMA steps: A-frags (LDS or global), B-frags DIRECT from global bf16.
// Fully unrolled -> all loads issued up front, deep MLP, no __syncthreads.
template <int NKB>
__device__ __forceinline__ void mfma_loop(const unsigned short* __restrict__ Ab,
                                          const unsigned short* __restrict__ Bb,
                                          f32x4* accs) {
#pragma unroll
    for (int kb = 0; kb < NKB; ++kb) {
        bf16x8 a = *(const bf16x8*)(Ab + kb * 32);
        bf16x8 b = *(const bf16x8*)(Bb + kb * 32);
        accs[kb & 3] = __builtin_amdgcn_mfma_f32_16x16x32_bf16(a, b, accs[kb & 3], 0, 0, 0);
    }
}

// 256 blocks x 256 threads, 1 block/CU. Block owns j0=bid*4; gate-rows m=jq*4+gate
// so C/D hands each lane all 4 gates of its (j,b): lane col lm=b, quad lq=jq, reg=gate.
// c-state in registers; h double-buffered in ws (bf16, [64 b][1024 j] row-major).
__global__ void __launch_bounds__(256, 1) rnn_kernel(Params p) {
    extern __shared__ __align__(16) unsigned short smem[];
    unsigned short* sWi0 = smem;
    unsigned short* sWh0 = sWi0 + 16 * WI0_ST;
    unsigned short* sWi1 = sWh0 + 16 * WST;
    unsigned short* sWh1 = sWi1 + 16 * WST;

    cg::grid_group grid = cg::this_grid();
    const int tid = threadIdx.x, bid = blockIdx.x;
    const int lane = tid & 63, w = tid >> 6;
    const int lm = lane & 15, lq = lane >> 4;
    const int bcol0 = w * 16;
    const int bb = bcol0 + lm;
    const int j0 = bid * 4, jj = j0 + lq;
    const int T = p.fcl[0];

    // ws (ushort): x80[64][128] | h0[2][64][1024] | h1[2][64][1024] | wlin_bf[64][1024]
    unsigned short* x80g = (unsigned short*)p.ws;
    unsigned short* h0g  = x80g + 64 * 128;
    unsigned short* h1g  = h0g + 2 * 65536;
    unsigned short* wlg  = h1g + 2 * 65536;

    // ---------------- init (identical structure to the round-2 passing kernel) ----------------
    for (int idx = tid; idx < 16 * 1024; idx += 256) {
        int m = idx >> 10, k = idx & 1023;
        int gi = m & 3, jq = m >> 2;
        size_t row = (size_t)(gi * HDIM + j0 + jq);
        sWh0[m * WST + k] = f2bf(p.Wh0[row * HDIM + k]);
        sWi1[m * WST + k] = f2bf(p.Wi1[row * HDIM + k]);
        sWh1[m * WST + k] = f2bf(p.Wh1[row * HDIM + k]);
    }
    for (int idx = tid; idx < 16 * WI0_ST; idx += 256) {
        int m = idx / WI0_ST, k = idx - m * WI0_ST;
        int gi = m & 3, jq = m >> 2;
        unsigned short v = 0;
        if (k < DDIM + PBDIM) v = f2bf(p.Wi0[(size_t)(gi * HDIM + j0 + jq) * (DDIM + PBDIM) + k]);
        sWi0[idx] = v;
    }
    int gid = bid * 256 + tid;            // 0..65535
    h0g[gid] = 0;
    h1g[gid] = 0;
    if (gid < 64 * 128) {                 // x80: [y(0..63)=0 | pb(64..79) | pad(80..127)=0]
        int b = gid >> 7, k = gid & 127;
        unsigned short v = 0;
        if (k >= 64 && k < 80) v = f2bf(p.mu_pb[p.label[b] * PBDIM + (k - 64)]);
        x80g[gid] = v;
    }
    if (bid < 16) {                       // Wlin -> bf16, row-major [64][1024]
        for (int i = 0; i < 16; ++i) {
            int e = bid * 4096 + i * 256 + tid;
            wlg[e] = f2bf(p.Wlin[e]);
        }
    }
    if (bid == 16 && tid < BDIM) {        // aux outputs
        int lbl = p.label[tid];
        float* out_lbl = p.out + (size_t)T * BDIM * DDIM;
        float* out_pb  = out_lbl + BDIM;
        float* out_mu  = out_pb + BDIM * PBDIM;
        float* out_lv  = out_mu + BDIM * PBDIM;
        out_lbl[tid] = (float)lbl;
        for (int q = 0; q < PBDIM; ++q) {
            float mu = p.mu_pb[lbl * PBDIM + q];
            float lv = p.logvar_pb[lbl * PBDIM + q];
            out_pb[tid * PBDIM + q] = mu;
            out_mu[tid * PBDIM + q] = mu;
            out_lv[tid * PBDIM + q] = lv;
        }
    }
    float bias0[4], bias1[4];
#pragma unroll
    for (int r = 0; r < 4; ++r) {
        bias0[r] = p.bi0[r * HDIM + jj] + p.bh0[r * HDIM + jj];
        bias1[r] = p.bi1[r * HDIM + jj] + p.bh1[r * HDIM + jj];
    }
    float blin4[4] = {0.f, 0.f, 0.f, 0.f};
    if (bid < 4) {
        int d0 = bid * 16 + lq * 4;
#pragma unroll
        for (int r = 0; r < 4; ++r) blin4[r] = p.blin[d0 + r];
    }
    float c0 = 0.f, c1 = 0.f;

    grid.sync();

    const f32x4 zf = {0.f, 0.f, 0.f, 0.f};
    int cur = 0;
    for (int t = 0; t < T; ++t) {
        // ---- phase A: gates0 = Wi0*[y;pb] + Wh0*h0(t-1) ----
        {
            f32x4 accs[4] = {zf, zf, zf, zf};
            mfma_loop<3>(sWi0 + lm * WI0_ST + 8 * lq,
                         x80g + (size_t)bb * 128 + 8 * lq, accs);
            mfma_loop<32>(sWh0 + lm * WST + 8 * lq,
                          h0g + (size_t)cur * 65536 + (size_t)bb * 1024 + 8 * lq, accs);
            f32x4 s = accs[0] + accs[1] + accs[2] + accs[3];
            float gi_ = s[0] + bias0[0], gf_ = s[1] + bias0[1];
            float gg_ = s[2] + bias0[2], go_ = s[3] + bias0[3];
            c0 = sigf(gf_) * c0 + sigf(gi_) * tanh_(gg_);
            float h = sigf(go_) * tanh_(c0);
            h0g[(cur ^ 1) * 65536 + bb * 1024 + jj] = f2bf(h);
        }
        grid.sync();
        // ---- phase B: gates1 = Wi1*h0(t) + Wh1*h1(t-1) ----
        {
            f32x4 accs[4] = {zf, zf, zf, zf};
            mfma_loop<32>(sWi1 + lm * WST + 8 * lq,
                          h0g + (size_t)(cur ^ 1) * 65536 + (size_t)bb * 1024 + 8 * lq, accs);
            mfma_loop<32>(sWh1 + lm * WST + 8 * lq,
                          h1g + (size_t)cur * 65536 + (size_t)bb * 1024 + 8 * lq, accs);
            f32x4 s = accs[0] + accs[1] + accs[2] + accs[3];
            float gi_ = s[0] + bias1[0], gf_ = s[1] + bias1[1];
            float gg_ = s[2] + bias1[2], go_ = s[3] + bias1[3];
            c1 = sigf(gf_) * c1 + sigf(gi_) * tanh_(gg_);
            float h = sigf(go_) * tanh_(c1);
            h1g[(cur ^ 1) * 65536 + bb * 1024 + jj] = f2bf(h);
        }
        grid.sync();
        // ---- phase C: y(t) = Wlin*h1(t) + blin; feeds x for t+1 (blocks 0..3) ----
        if (bid < 4) {
            f32x4 accs[4] = {zf, zf, zf, zf};
            mfma_loop<32>(wlg + (size_t)(bid * 16 + lm) * 1024 + 8 * lq,
                          h1g + (size_t)(cur ^ 1) * 65536 + (size_t)bb * 1024 + 8 * lq, accs);
            f32x4 s = accs[0] + accs[1] + accs[2] + accs[3];
            int d0 = bid * 16 + lq * 4;
            float4 y4;
            y4.x = s[0] + blin4[0]; y4.y = s[1] + blin4[1];
            y4.z = s[2] + blin4[2]; y4.w = s[3] + blin4[3];
            *(float4*)(p.out + (size_t)t * BDIM * DDIM + bb * DDIM + d0) = y4;
            ushort4 u4;
            u4.x = f2bf(y4.x); u4.y = f2bf(y4.y); u4.z = f2bf(y4.z); u4.w = f2bf(y4.w);
            *(ushort4*)(x80g + bb * 128 + d0) = u4;
        }
        grid.sync();
        cur ^= 1;
    }
}

extern "C" void kernel_launch(void* const* d_in, const int* in_sizes, int n_in,
                              void* d_out, int out_size, void* d_ws, size_t ws_size,
                              hipStream_t stream) {
    Params p;
    p.label     = (const int*)d_in[0];
    p.fcl       = (const int*)d_in[1];
    p.mu_pb     = (const float*)d_in[2];
    p.logvar_pb = (const float*)d_in[3];
    p.Wi0       = (const float*)d_in[4];
    p.Wh0       = (const float*)d_in[5];
    p.bi0       = (const float*)d_in[6];
    p.bh0       = (const float*)d_in[7];
    p.Wi1       = (const float*)d_in[8];
    p.Wh1       = (const float*)d_in[9];
    p.bi1       = (const float*)d_in[10];
    p.bh1       = (const float*)d_in[11];
    p.Wlin      = (const float*)d_in[12];
    p.blin      = (const float*)d_in[13];
    p.out       = (float*)d_out;
    p.ws        = (float*)d_ws;

    (void)hipFuncSetAttribute((const void*)rnn_kernel,
                              hipFuncAttributeMaxDynamicSharedMemorySize, SMEM_BYTES);
    void* args[] = { &p };
    (void)hipLaunchCooperativeKernel((void*)rnn_kernel, dim3(256), dim3(256), args,
                                     SMEM_BYTES, stream);
}

// Round 5
// 19890.620 us; speedup vs baseline: 3.4279x; 1.4094x over previous
//
#include <hip/hip_runtime.h>
#include <hip/hip_cooperative_groups.h>
#include <math.h>

#define NUM_PB 32
#define PBDIM  16
#define DDIM   64
#define HDIM   1024
#define BDIM   64

namespace cg = cooperative_groups;

typedef __attribute__((ext_vector_type(8))) short bf16x8;
typedef __attribute__((ext_vector_type(4))) float f32x4;

// LDS: weights only. strides in shorts; both give 16B-aligned rows.
#define WI0_ST 104                       // 96 + 8 pad (208 B = 13*16)
#define WST    1032                      // 1024 + 8 pad (2064 B = 129*16)
#define SMEM_BYTES ((16 * WI0_ST + 3 * 16 * WST) * 2)   // 102400 B

struct Params {
    const int*   label;
    const int*   fcl;
    const float* mu_pb;
    const float* logvar_pb;
    const float* Wi0;
    const float* Wh0;
    const float* bi0;
    const float* bh0;
    const float* Wi1;
    const float* Wh1;
    const float* bi1;
    const float* bh1;
    const float* Wlin;
    const float* blin;
    float*       out;
    float*       ws;
};

__device__ __forceinline__ unsigned short f2bf(float x) {
    unsigned int u = __builtin_bit_cast(unsigned int, x);
    u += 0x7fffu + ((u >> 16) & 1u);     // RNE
    return (unsigned short)(u >> 16);
}
__device__ __forceinline__ float sigf(float x)  { return 1.0f / (1.0f + __expf(-x)); }
__device__ __forceinline__ float tanh_(float x) { float e = __expf(2.0f * x); return 1.0f - 2.0f / (e + 1.0f); }

// NKB MFMA steps: A-frags (LDS or global), B-frags DIRECT from global bf16.
template <int NKB>
__device__ __forceinline__ void mfma_loop(const unsigned short* __restrict__ Ab,
                                          const unsigned short* __restrict__ Bb,
                                          f32x4* accs) {
#pragma unroll
    for (int kb = 0; kb < NKB; ++kb) {
        bf16x8 a = *(const bf16x8*)(Ab + kb * 32);
        bf16x8 b = *(const bf16x8*)(Bb + kb * 32);
        accs[kb & 3] = __builtin_amdgcn_mfma_f32_16x16x32_bf16(a, b, accs[kb & 3], 0, 0, 0);
    }
}

// Two-level monotonic grid barrier. Leaf g (8 groups of 32 blocks) and root
// counters live in the never-read k=[96,128) padding of x80 (zeroed in init,
// published by the one cg::grid.sync()). Monotonic => no reset race.
// Agent-scope acq_rel gives the same cross-XCD visibility cg sync provided.
__device__ __forceinline__ void gbar(char* wsBase, int bid, int tid, unsigned barIdx) {
    __syncthreads();
    if (tid == 0) {
        int g = bid >> 5;
        unsigned* leaf = (unsigned*)(wsBase + 192 + g * 512);   // row 2g, byte 192
        unsigned* root = (unsigned*)(wsBase + 16 * 256 + 192);  // row 16, byte 192
        unsigned old = __hip_atomic_fetch_add(leaf, 1u, __ATOMIC_ACQ_REL, __HIP_MEMORY_SCOPE_AGENT);
        if (old == barIdx * 32u - 1u)
            __hip_atomic_fetch_add(root, 1u, __ATOMIC_ACQ_REL, __HIP_MEMORY_SCOPE_AGENT);
        while (__hip_atomic_load(root, __ATOMIC_ACQUIRE, __HIP_MEMORY_SCOPE_AGENT) < barIdx * 8u)
            __builtin_amdgcn_s_sleep(1);
    }
    __syncthreads();
}

// 256 blocks x 256 threads, 1 block/CU. Block owns j0=bid*4; gate-rows m=jq*4+gate
// so C/D hands each lane all 4 gates of its (j,b): lane col lm=b, quad lq=jq, reg=gate.
__global__ void __launch_bounds__(256, 1) rnn_kernel(Params p) {
    extern __shared__ __align__(16) unsigned short smem[];
    unsigned short* sWi0 = smem;
    unsigned short* sWh0 = sWi0 + 16 * WI0_ST;
    unsigned short* sWi1 = sWh0 + 16 * WST;
    unsigned short* sWh1 = sWi1 + 16 * WST;

    cg::grid_group grid = cg::this_grid();
    const int tid = threadIdx.x, bid = blockIdx.x;
    const int lane = tid & 63, w = tid >> 6;
    const int lm = lane & 15, lq = lane >> 4;
    const int bcol0 = w * 16;
    const int bb = bcol0 + lm;
    const int j0 = bid * 4, jj = j0 + lq;
    const int T = p.fcl[0];

    // ws (ushort): x80[64][128] (barrier counters in k>=96 padding) | h0[2][64][1024]
    //              | h1[2][64][1024] | wlin_bf[64][1024]
    unsigned short* x80g = (unsigned short*)p.ws;
    unsigned short* h0g  = x80g + 64 * 128;
    unsigned short* h1g  = h0g + 2 * 65536;
    unsigned short* wlg  = h1g + 2 * 65536;

    // ---------------- init ----------------
    for (int idx = tid; idx < 16 * 1024; idx += 256) {
        int m = idx >> 10, k = idx & 1023;
        int gi = m & 3, jq = m >> 2;
        size_t row = (size_t)(gi * HDIM + j0 + jq);
        sWh0[m * WST + k] = f2bf(p.Wh0[row * HDIM + k]);
        sWi1[m * WST + k] = f2bf(p.Wi1[row * HDIM + k]);
        sWh1[m * WST + k] = f2bf(p.Wh1[row * HDIM + k]);
    }
    for (int idx = tid; idx < 16 * WI0_ST; idx += 256) {
        int m = idx / WI0_ST, k = idx - m * WI0_ST;
        int gi = m & 3, jq = m >> 2;
        unsigned short v = 0;
        if (k < DDIM + PBDIM) v = f2bf(p.Wi0[(size_t)(gi * HDIM + j0 + jq) * (DDIM + PBDIM) + k]);
        sWi0[idx] = v;
    }
    int gid = bid * 256 + tid;            // 0..65535
    h0g[gid] = 0;
    h1g[gid] = 0;
    if (gid < 64 * 128) {                 // x80: [y(0..63)=0 | pb(64..79) | pad(80..127)=0]
        int b = gid >> 7, k = gid & 127;  // pad zeroing also zeroes barrier counters
        unsigned short v = 0;
        if (k >= 64 && k < 80) v = f2bf(p.mu_pb[p.label[b] * PBDIM + (k - 64)]);
        x80g[gid] = v;
    }
    if (bid < 16) {                       // Wlin -> bf16, row-major [64][1024]
        for (int i = 0; i < 16; ++i) {
            int e = bid * 4096 + i * 256 + tid;
            wlg[e] = f2bf(p.Wlin[e]);
        }
    }
    if (bid == 16 && tid < BDIM) {        // aux outputs
        int lbl = p.label[tid];
        float* out_lbl = p.out + (size_t)T * BDIM * DDIM;
        float* out_pb  = out_lbl + BDIM;
        float* out_mu  = out_pb + BDIM * PBDIM;
        float* out_lv  = out_mu + BDIM * PBDIM;
        out_lbl[tid] = (float)lbl;
        for (int q = 0; q < PBDIM; ++q) {
            float mu = p.mu_pb[lbl * PBDIM + q];
            float lv = p.logvar_pb[lbl * PBDIM + q];
            out_pb[tid * PBDIM + q] = mu;
            out_mu[tid * PBDIM + q] = mu;
            out_lv[tid * PBDIM + q] = lv;
        }
    }
    float bias0[4], bias1[4];
#pragma unroll
    for (int r = 0; r < 4; ++r) {
        bias0[r] = p.bi0[r * HDIM + jj] + p.bh0[r * HDIM + jj];
        bias1[r] = p.bi1[r * HDIM + jj] + p.bh1[r * HDIM + jj];
    }
    float blin4[4] = {0.f, 0.f, 0.f, 0.f};
    if (bid < 4) {
        int d0 = bid * 16 + lq * 4;
#pragma unroll
        for (int r = 0; r < 4; ++r) blin4[r] = p.blin[d0 + r];
    }
    float c0 = 0.f, c1 = 0.f;
    char* wsBase = (char*)p.ws;

    grid.sync();   // publishes zeroed barrier counters + all init state

    const f32x4 zf = {0.f, 0.f, 0.f, 0.f};
    int cur = 0;
    unsigned barIdx = 0;
    for (int t = 0; t < T; ++t) {
        // ---- phase A: gates0 = Wi0*[y;pb] + Wh0*h0(t-1) ----
        {
            f32x4 accs[4] = {zf, zf, zf, zf};
            mfma_loop<3>(sWi0 + lm * WI0_ST + 8 * lq,
                         x80g + (size_t)bb * 128 + 8 * lq, accs);
            mfma_loop<32>(sWh0 + lm * WST + 8 * lq,
                          h0g + (size_t)cur * 65536 + (size_t)bb * 1024 + 8 * lq, accs);
            f32x4 s = accs[0] + accs[1] + accs[2] + accs[3];
            float gi_ = s[0] + bias0[0], gf_ = s[1] + bias0[1];
            float gg_ = s[2] + bias0[2], go_ = s[3] + bias0[3];
            c0 = sigf(gf_) * c0 + sigf(gi_) * tanh_(gg_);
            float h = sigf(go_) * tanh_(c0);
            h0g[(cur ^ 1) * 65536 + bb * 1024 + jj] = f2bf(h);
        }
        gbar(wsBase, bid, tid, ++barIdx);
        // ---- phase B: gates1 = Wi1*h0(t) + Wh1*h1(t-1) ----
        {
            f32x4 accs[4] = {zf, zf, zf, zf};
            mfma_loop<32>(sWi1 + lm * WST + 8 * lq,
                          h0g + (size_t)(cur ^ 1) * 65536 + (size_t)bb * 1024 + 8 * lq, accs);
            mfma_loop<32>(sWh1 + lm * WST + 8 * lq,
                          h1g + (size_t)cur * 65536 + (size_t)bb * 1024 + 8 * lq, accs);
            f32x4 s = accs[0] + accs[1] + accs[2] + accs[3];
            float gi_ = s[0] + bias1[0], gf_ = s[1] + bias1[1];
            float gg_ = s[2] + bias1[2], go_ = s[3] + bias1[3];
            c1 = sigf(gf_) * c1 + sigf(gi_) * tanh_(gg_);
            float h = sigf(go_) * tanh_(c1);
            h1g[(cur ^ 1) * 65536 + bb * 1024 + jj] = f2bf(h);
        }
        gbar(wsBase, bid, tid, ++barIdx);
        // ---- phase C: y(t) = Wlin*h1(t) + blin; feeds x for t+1 (blocks 0..3) ----
        if (bid < 4) {
            f32x4 accs[4] = {zf, zf, zf, zf};
            mfma_loop<32>(wlg + (size_t)(bid * 16 + lm) * 1024 + 8 * lq,
                          h1g + (size_t)(cur ^ 1) * 65536 + (size_t)bb * 1024 + 8 * lq, accs);
            f32x4 s = accs[0] + accs[1] + accs[2] + accs[3];
            int d0 = bid * 16 + lq * 4;
            float4 y4;
            y4.x = s[0] + blin4[0]; y4.y = s[1] + blin4[1];
            y4.z = s[2] + blin4[2]; y4.w = s[3] + blin4[3];
            *(float4*)(p.out + (size_t)t * BDIM * DDIM + bb * DDIM + d0) = y4;
            ushort4 u4;
            u4.x = f2bf(y4.x); u4.y = f2bf(y4.y); u4.z = f2bf(y4.z); u4.w = f2bf(y4.w);
            *(ushort4*)(x80g + bb * 128 + d0) = u4;
        }
        gbar(wsBase, bid, tid, ++barIdx);
        cur ^= 1;
    }
}

extern "C" void kernel_launch(void* const* d_in, const int* in_sizes, int n_in,
                              void* d_out, int out_size, void* d_ws, size_t ws_size,
                              hipStream_t stream) {
    Params p;
    p.label     = (const int*)d_in[0];
    p.fcl       = (const int*)d_in[1];
    p.mu_pb     = (const float*)d_in[2];
    p.logvar_pb = (const float*)d_in[3];
    p.Wi0       = (const float*)d_in[4];
    p.Wh0       = (const float*)d_in[5];
    p.bi0       = (const float*)d_in[6];
    p.bh0       = (const float*)d_in[7];
    p.Wi1       = (const float*)d_in[8];
    p.Wh1       = (const float*)d_in[9];
    p.bi1       = (const float*)d_in[10];
    p.bh1       = (const float*)d_in[11];
    p.Wlin      = (const float*)d_in[12];
    p.blin      = (const float*)d_in[13];
    p.out       = (float*)d_out;
    p.ws        = (float*)d_ws;

    (void)hipFuncSetAttribute((const void*)rnn_kernel,
                              hipFuncAttributeMaxDynamicSharedMemorySize, SMEM_BYTES);
    void* args[] = { &p };
    (void)hipLaunchCooperativeKernel((void*)rnn_kernel, dim3(256), dim3(256), args,
                                     SMEM_BYTES, stream);
}

// Round 7
// 12618.813 us; speedup vs baseline: 5.4033x; 1.5763x over previous
//
#include <hip/hip_runtime.h>
#include <hip/hip_cooperative_groups.h>
#include <math.h>

#define NUM_PB 32
#define PBDIM  16
#define DDIM   64
#define HDIM   1024
#define BDIM   64

namespace cg = cooperative_groups;

typedef __attribute__((ext_vector_type(8))) short bf16x8;
typedef __attribute__((ext_vector_type(4))) float f32x4;

// LDS: weights only. strides in shorts; both give 16B-aligned rows.
#define WI0_ST 104                       // 96 + 8 pad (208 B = 13*16)
#define WST    1032                      // 1024 + 8 pad (2064 B = 129*16)
#define SMEM_BYTES ((16 * WI0_ST + 3 * 16 * WST) * 2)   // 102400 B

struct Params {
    const int*   label;
    const int*   fcl;
    const float* mu_pb;
    const float* logvar_pb;
    const float* Wi0;
    const float* Wh0;
    const float* bi0;
    const float* bh0;
    const float* Wi1;
    const float* Wh1;
    const float* bi1;
    const float* bh1;
    const float* Wlin;
    const float* blin;
    float*       out;
    float*       ws;
};

__device__ __forceinline__ unsigned short f2bf(float x) {
    unsigned int u = __builtin_bit_cast(unsigned int, x);
    u += 0x7fffu + ((u >> 16) & 1u);     // RNE
    return (unsigned short)(u >> 16);
}
__device__ __forceinline__ float sigf(float x)  { return 1.0f / (1.0f + __expf(-x)); }
__device__ __forceinline__ float tanh_(float x) { float e = __expf(2.0f * x); return 1.0f - 2.0f / (e + 1.0f); }

// NKB MFMA steps: A-frags (LDS or global), B-frags DIRECT from global bf16.
template <int NKB>
__device__ __forceinline__ void mfma_loop(const unsigned short* __restrict__ Ab,
                                          const unsigned short* __restrict__ Bb,
                                          f32x4* accs) {
#pragma unroll
    for (int kb = 0; kb < NKB; ++kb) {
        bf16x8 a = *(const bf16x8*)(Ab + kb * 32);
        bf16x8 b = *(const bf16x8*)(Bb + kb * 32);
        accs[kb & 3] = __builtin_amdgcn_mfma_f32_16x16x32_bf16(a, b, accs[kb & 3], 0, 0, 0);
    }
}

// Two-level monotonic grid barrier (round-5 layout, round-7 fence discipline):
// release fence once before arrival; relaxed RMW arrivals; RELAXED poll loads
// (no per-iteration cache invalidate); one acquire fence after the wait.
// Counters live in the never-read k=[96,128) padding of x80 (zeroed in init,
// published by the one cg::grid.sync()). Monotonic => no reset race.
__device__ __forceinline__ void gbar(char* wsBase, int bid, int tid, unsigned barIdx) {
    __syncthreads();
    if (tid == 0) {
        __builtin_amdgcn_fence(__ATOMIC_RELEASE, "agent");
        int g = bid >> 5;
        unsigned* leaf = (unsigned*)(wsBase + 192 + g * 512);   // row 2g, byte 192
        unsigned* root = (unsigned*)(wsBase + 16 * 256 + 192);  // row 16, byte 192
        unsigned old = __hip_atomic_fetch_add(leaf, 1u, __ATOMIC_RELAXED, __HIP_MEMORY_SCOPE_AGENT);
        if (old == barIdx * 32u - 1u)
            __hip_atomic_fetch_add(root, 1u, __ATOMIC_RELAXED, __HIP_MEMORY_SCOPE_AGENT);
        while (__hip_atomic_load(root, __ATOMIC_RELAXED, __HIP_MEMORY_SCOPE_AGENT) < barIdx * 8u)
            __builtin_amdgcn_s_sleep(1);
        __builtin_amdgcn_fence(__ATOMIC_ACQUIRE, "agent");
    }
    __syncthreads();
}

// 256 blocks x 256 threads, 1 block/CU. Block owns j0=bid*4; gate-rows m=jq*4+gate
// so C/D hands each lane all 4 gates of its (j,b): lane col lm=b, quad lq=jq, reg=gate.
__global__ void __launch_bounds__(256, 1) rnn_kernel(Params p) {
    extern __shared__ __align__(16) unsigned short smem[];
    unsigned short* sWi0 = smem;
    unsigned short* sWh0 = sWi0 + 16 * WI0_ST;
    unsigned short* sWi1 = sWh0 + 16 * WST;
    unsigned short* sWh1 = sWi1 + 16 * WST;

    cg::grid_group grid = cg::this_grid();
    const int tid = threadIdx.x, bid = blockIdx.x;
    const int lane = tid & 63, w = tid >> 6;
    const int lm = lane & 15, lq = lane >> 4;
    const int bcol0 = w * 16;
    const int bb = bcol0 + lm;
    const int j0 = bid * 4, jj = j0 + lq;
    const int T = p.fcl[0];

    // ws (ushort): x80[64][128] (barrier counters in k>=96 padding) | h0[2][64][1024]
    //              | h1[2][64][1024] | wlin_bf[64][1024]
    unsigned short* x80g = (unsigned short*)p.ws;
    unsigned short* h0g  = x80g + 64 * 128;
    unsigned short* h1g  = h0g + 2 * 65536;
    unsigned short* wlg  = h1g + 2 * 65536;

    // ---------------- init ----------------
    for (int idx = tid; idx < 16 * 1024; idx += 256) {
        int m = idx >> 10, k = idx & 1023;
        int gi = m & 3, jq = m >> 2;
        size_t row = (size_t)(gi * HDIM + j0 + jq);
        sWh0[m * WST + k] = f2bf(p.Wh0[row * HDIM + k]);
        sWi1[m * WST + k] = f2bf(p.Wi1[row * HDIM + k]);
        sWh1[m * WST + k] = f2bf(p.Wh1[row * HDIM + k]);
    }
    for (int idx = tid; idx < 16 * WI0_ST; idx += 256) {
        int m = idx / WI0_ST, k = idx - m * WI0_ST;
        int gi = m & 3, jq = m >> 2;
        unsigned short v = 0;
        if (k < DDIM + PBDIM) v = f2bf(p.Wi0[(size_t)(gi * HDIM + j0 + jq) * (DDIM + PBDIM) + k]);
        sWi0[idx] = v;
    }
    int gid = bid * 256 + tid;            // 0..65535
    h0g[gid] = 0;
    h1g[gid] = 0;
    if (gid < 64 * 128) {                 // x80: [y(0..63)=0 | pb(64..79) | pad(80..127)=0]
        int b = gid >> 7, k = gid & 127;  // pad zeroing also zeroes barrier counters
        unsigned short v = 0;
        if (k >= 64 && k < 80) v = f2bf(p.mu_pb[p.label[b] * PBDIM + (k - 64)]);
        x80g[gid] = v;
    }
    if (bid < 16) {                       // Wlin -> bf16, row-major [64][1024]
        for (int i = 0; i < 16; ++i) {
            int e = bid * 4096 + i * 256 + tid;
            wlg[e] = f2bf(p.Wlin[e]);
        }
    }
    if (bid == 16 && tid < BDIM) {        // aux outputs
        int lbl = p.label[tid];
        float* out_lbl = p.out + (size_t)T * BDIM * DDIM;
        float* out_pb  = out_lbl + BDIM;
        float* out_mu  = out_pb + BDIM * PBDIM;
        float* out_lv  = out_mu + BDIM * PBDIM;
        out_lbl[tid] = (float)lbl;
        for (int q = 0; q < PBDIM; ++q) {
            float mu = p.mu_pb[lbl * PBDIM + q];
            float lv = p.logvar_pb[lbl * PBDIM + q];
            out_pb[tid * PBDIM + q] = mu;
            out_mu[tid * PBDIM + q] = mu;
            out_lv[tid * PBDIM + q] = lv;
        }
    }
    float bias0[4], bias1[4];
#pragma unroll
    for (int r = 0; r < 4; ++r) {
        bias0[r] = p.bi0[r * HDIM + jj] + p.bh0[r * HDIM + jj];
        bias1[r] = p.bi1[r * HDIM + jj] + p.bh1[r * HDIM + jj];
    }
    float blin4[4] = {0.f, 0.f, 0.f, 0.f};
    if (bid < 4) {
        int d0 = bid * 16 + lq * 4;
#pragma unroll
        for (int r = 0; r < 4; ++r) blin4[r] = p.blin[d0 + r];
    }
    float c0 = 0.f, c1 = 0.f;
    char* wsBase = (char*)p.ws;

    grid.sync();   // publishes zeroed barrier counters + all init state

    const f32x4 zf = {0.f, 0.f, 0.f, 0.f};
    int cur = 0;
    unsigned barIdx = 0;
    for (int t = 0; t < T; ++t) {
        // ---- phase A: gates0 = Wi0*[y;pb] + Wh0*h0(t-1) ----
        {
            f32x4 accs[4] = {zf, zf, zf, zf};
            mfma_loop<3>(sWi0 + lm * WI0_ST + 8 * lq,
                         x80g + (size_t)bb * 128 + 8 * lq, accs);
            mfma_loop<32>(sWh0 + lm * WST + 8 * lq,
                          h0g + (size_t)cur * 65536 + (size_t)bb * 1024 + 8 * lq, accs);
            f32x4 s = accs[0] + accs[1] + accs[2] + accs[3];
            float gi_ = s[0] + bias0[0], gf_ = s[1] + bias0[1];
            float gg_ = s[2] + bias0[2], go_ = s[3] + bias0[3];
            c0 = sigf(gf_) * c0 + sigf(gi_) * tanh_(gg_);
            float h = sigf(go_) * tanh_(c0);
            h0g[(cur ^ 1) * 65536 + bb * 1024 + jj] = f2bf(h);
        }
        gbar(wsBase, bid, tid, ++barIdx);
        // ---- phase B: gates1 = Wi1*h0(t) + Wh1*h1(t-1) ----
        {
            f32x4 accs[4] = {zf, zf, zf, zf};
            mfma_loop<32>(sWi1 + lm * WST + 8 * lq,
                          h0g + (size_t)(cur ^ 1) * 65536 + (size_t)bb * 1024 + 8 * lq, accs);
            mfma_loop<32>(sWh1 + lm * WST + 8 * lq,
                          h1g + (size_t)cur * 65536 + (size_t)bb * 1024 + 8 * lq, accs);
            f32x4 s = accs[0] + accs[1] + accs[2] + accs[3];
            float gi_ = s[0] + bias1[0], gf_ = s[1] + bias1[1];
            float gg_ = s[2] + bias1[2], go_ = s[3] + bias1[3];
            c1 = sigf(gf_) * c1 + sigf(gi_) * tanh_(gg_);
            float h = sigf(go_) * tanh_(c1);
            h1g[(cur ^ 1) * 65536 + bb * 1024 + jj] = f2bf(h);
        }
        gbar(wsBase, bid, tid, ++barIdx);
        // ---- phase C: y(t) = Wlin*h1(t) + blin; feeds x for t+1 (blocks 0..3) ----
        if (bid < 4) {
            f32x4 accs[4] = {zf, zf, zf, zf};
            mfma_loop<32>(wlg + (size_t)(bid * 16 + lm) * 1024 + 8 * lq,
                          h1g + (size_t)(cur ^ 1) * 65536 + (size_t)bb * 1024 + 8 * lq, accs);
            f32x4 s = accs[0] + accs[1] + accs[2] + accs[3];
            int d0 = bid * 16 + lq * 4;
            float4 y4;
            y4.x = s[0] + blin4[0]; y4.y = s[1] + blin4[1];
            y4.z = s[2] + blin4[2]; y4.w = s[3] + blin4[3];
            *(float4*)(p.out + (size_t)t * BDIM * DDIM + bb * DDIM + d0) = y4;
            ushort4 u4;
            u4.x = f2bf(y4.x); u4.y = f2bf(y4.y); u4.z = f2bf(y4.z); u4.w = f2bf(y4.w);
            *(ushort4*)(x80g + bb * 128 + d0) = u4;
        }
        gbar(wsBase, bid, tid, ++barIdx);
        cur ^= 1;
    }
}

extern "C" void kernel_launch(void* const* d_in, const int* in_sizes, int n_in,
                              void* d_out, int out_size, void* d_ws, size_t ws_size,
                              hipStream_t stream) {
    Params p;
    p.label     = (const int*)d_in[0];
    p.fcl       = (const int*)d_in[1];
    p.mu_pb     = (const float*)d_in[2];
    p.logvar_pb = (const float*)d_in[3];
    p.Wi0       = (const float*)d_in[4];
    p.Wh0       = (const float*)d_in[5];
    p.bi0       = (const float*)d_in[6];
    p.bh0       = (const float*)d_in[7];
    p.Wi1       = (const float*)d_in[8];
    p.Wh1       = (const float*)d_in[9];
    p.bi1       = (const float*)d_in[10];
    p.bh1       = (const float*)d_in[11];
    p.Wlin      = (const float*)d_in[12];
    p.blin      = (const float*)d_in[13];
    p.out       = (float*)d_out;
    p.ws        = (float*)d_ws;

    (void)hipFuncSetAttribute((const void*)rnn_kernel,
                              hipFuncAttributeMaxDynamicSharedMemorySize, SMEM_BYTES);
    void* args[] = { &p };
    (void)hipLaunchCooperativeKernel((void*)rnn_kernel, dim3(256), dim3(256), args,
                                     SMEM_BYTES, stream);
}